// Round 3
// baseline (872.105 us; speedup 1.0000x reference)
//
#include <hip/hip_runtime.h>

// Ensemble of 8 LSTMs (H=64, input dim 1) over T=1024, B=128, then (B,T)@Wl^T+bl.
//
// v3: latency-hiding via chain co-location + reduced issue.
//  - 32 blocks x 512 threads; each block runs TWO independent chains (l, 16-batch
//    group), 4 waves each -> 2 waves/SIMD on 32 CUs; sibling chain fills stalls.
//  - gates(16x256) = h(16x64) @ Whh^T via mfma_f32_16x16x32_bf16.
//    Precision: Whh kept exact as bf16 hi+lo pair (2^-18), h rounded to ONE bf16
//    per step -> 4 MFMAs per gate-group (was 6), 2 ds_read_b128 (was 4).
//  - logistic constants folded into Whh/Wih/bias at load: sigmoid gates scaled
//    1/ln2, tanh gate scaled 2/ln2 -> activations need no input multiply.
//  - h stores packed with v_cvt_pk_bf16_f32.
//  - D-layout (col=lane&15=unit, row=(lane>>4)*4+reg=batch): i,f,g,o of a
//    (batch,unit) land in the same lane -> in-register cell update.

#define LENA 8
#define NB 128
#define NT 1024
#define NH 64

typedef __attribute__((ext_vector_type(4))) float f32x4;
typedef __attribute__((ext_vector_type(8))) short bf16x8;

__device__ __forceinline__ short f2bf(float f) {
    unsigned u = __float_as_uint(f);
    unsigned r = (u + 0x7FFFu + ((u >> 16) & 1u)) >> 16;
    return (short)r;
}
__device__ __forceinline__ float bf2f(short s) {
    return __uint_as_float(((unsigned)(unsigned short)s) << 16);
}

__global__ __launch_bounds__(512, 1) void lstm_mfma2_kernel(
    const float* __restrict__ x, const float* __restrict__ hn,
    const float* __restrict__ Wih, const float* __restrict__ Whh,
    const float* __restrict__ bih, const float* __restrict__ bhh,
    const float* __restrict__ Wl, float* __restrict__ ws)
{
    __shared__ float wl_lds[NT][LENA];                        // 32 KB (Wl^T), shared by both chains
    __shared__ __align__(16) short hbuf[2][2][16 * NH];       // [chain][parity], bf16 h, 8 KB
    __shared__ float h63buf[2][2][16];                        // [chain][parity]

    const int tid = threadIdx.x;
    const int cid = tid >> 8;        // chain within block (0/1)
    const int w   = (tid >> 6) & 3;  // wave within chain: owns units 16w..16w+15
    const int l   = tid & 63;        // lane
    const int c   = blockIdx.x * 2 + cid;   // global chain 0..63
    const int li  = c >> 3;          // LSTM index
    const int bg  = c & 7;           // batch group (16 batches)

    // ---- staging ----
    for (int i = tid; i < NT * LENA; i += 512) {
        int a = i >> 10, t = i & (NT - 1);
        wl_lds[t][a] = Wl[a * NT + t];
    }
    for (int i = tid; i < 2 * 16 * NH; i += 512) {
        int cc = i >> 10;
        int b = (i >> 6) & 15, u = i & 63;
        int c2 = blockIdx.x * 2 + cc;
        float v = hn[((size_t)(c2 >> 3) * NB + (c2 & 7) * 16 + b) * NH + u];
        int idx = b * 64 + ((((u >> 3) ^ (b & 7)) << 3) | (u & 7));
        hbuf[cc][0][idx] = f2bf(v);
    }

    // ---- per-lane persistent B fragments (scaled Whh, exact via bf16 hi+lo) ----
    const int bq = l & 15, kg = l >> 4;
    const float RLN2 = 1.44269504f;            // 1/ln2 (sigmoid gates)
    bf16x8 bhf[4][2], blf[4][2];
    float biasv[4], wihv[4];
    #pragma unroll
    for (int G = 0; G < 4; ++G) {
        const float scale = (G == 2) ? 2.0f * RLN2 : RLN2;   // tanh gate gets 2/ln2
        int row = 64 * G + 16 * w + bq;
        const float* rp = Whh + ((size_t)li * 256 + row) * 64 + kg * 8;
        #pragma unroll
        for (int kt = 0; kt < 2; ++kt) {
            const float* q = rp + kt * 32;
            #pragma unroll
            for (int e = 0; e < 8; ++e) {
                float f = scale * q[e];
                short hi = f2bf(f);
                bhf[G][kt][e] = hi;
                blf[G][kt][e] = f2bf(f - bf2f(hi));
            }
        }
        biasv[G] = scale * (bih[li * 256 + row] + bhh[li * 256 + row]);
        wihv[G]  = scale * Wih[li * 256 + row];
    }

    // x prefetch: lane's 4 batches are 4*kg..4*kg+3 (D rows)
    const float* xp0 = x + ((size_t)bg * 16 + kg * 4 + 0) * NT;
    const float* xp1 = xp0 + NT;
    const float* xp2 = xp0 + 2 * NT;
    const float* xp3 = xp0 + 3 * NT;
    float xc0 = xp0[0], xc1 = xp1[0], xc2 = xp2[0], xc3 = xp3[0];

    // A-fragment LDS offsets (swizzled): slot s = (u>>3), pos = (s ^ (b&7))<<3
    const int ia0 = bq * 64 + (((0 + kg) ^ (bq & 7)) << 3);
    const int ia1 = bq * 64 + (((4 + kg) ^ (bq & 7)) << 3);

    // h write indices: unit uu = 16w+bq, batches 4kg+r
    const int uu = 16 * w + bq;
    int wi[4];
    #pragma unroll
    for (int r = 0; r < 4; ++r) {
        int b = 4 * kg + r;
        wi[r] = b * 64 + ((((uu >> 3) ^ (b & 7)) << 3) | (uu & 7));
    }

    // projection roles (per chain): waves 0,1 accumulate out partials
    const bool dop  = (w < 2);
    const int  pb   = (w & 1) * 8 + (l >> 3);   // batch 0..15
    const int  pa   = l & 7;                    // output col 0..7
    const bool do63 = (w == 3) && (bq == 15);   // lanes owning unit 63
    float pacc = 0.0f;
    float cst0 = 0.0f, cst1 = 0.0f, cst2 = 0.0f, cst3 = 0.0f;

    __syncthreads();

    #pragma unroll 2
    for (int t = 0; t < NT; ++t) {
        const int p = t & 1;

        if (dop && t > 0)
            pacc = fmaf(h63buf[cid][p][pb], wl_lds[t - 1][pa], pacc);

        int t1 = (t < NT - 1) ? t + 1 : t;
        float xn0 = xp0[t1], xn1 = xp1[t1], xn2 = xp2[t1], xn3 = xp3[t1];

        bf16x8 ah0 = *(const bf16x8*)&hbuf[cid][p][ia0];
        bf16x8 ah1 = *(const bf16x8*)&hbuf[cid][p][ia1];

        f32x4 acc[4];
        #pragma unroll
        for (int G = 0; G < 4; ++G) {
            f32x4 a;
            a[0] = fmaf(xc0, wihv[G], biasv[G]);
            a[1] = fmaf(xc1, wihv[G], biasv[G]);
            a[2] = fmaf(xc2, wihv[G], biasv[G]);
            a[3] = fmaf(xc3, wihv[G], biasv[G]);
            a = __builtin_amdgcn_mfma_f32_16x16x32_bf16(ah0, bhf[G][0], a, 0, 0, 0);
            a = __builtin_amdgcn_mfma_f32_16x16x32_bf16(ah1, bhf[G][1], a, 0, 0, 0);
            a = __builtin_amdgcn_mfma_f32_16x16x32_bf16(ah0, blf[G][0], a, 0, 0, 0);
            a = __builtin_amdgcn_mfma_f32_16x16x32_bf16(ah1, blf[G][1], a, 0, 0, 0);
            acc[G] = a;
        }

        float hh[4];
        #pragma unroll
        for (int r = 0; r < 4; ++r) {
            // gates pre-scaled by 1/ln2 (2/ln2 for g) -> activations use exp2 directly
            float iv = __builtin_amdgcn_rcpf(1.0f + __builtin_amdgcn_exp2f(-acc[0][r]));
            float fv = __builtin_amdgcn_rcpf(1.0f + __builtin_amdgcn_exp2f(-acc[1][r]));
            float gt = fmaf(-2.0f, __builtin_amdgcn_rcpf(1.0f + __builtin_amdgcn_exp2f(acc[2][r])), 1.0f);
            float ov = __builtin_amdgcn_rcpf(1.0f + __builtin_amdgcn_exp2f(-acc[3][r]));
            float& cs = (r == 0) ? cst0 : (r == 1) ? cst1 : (r == 2) ? cst2 : cst3;
            cs = fmaf(fv, cs, iv * gt);
            float ct = fmaf(-2.0f, __builtin_amdgcn_rcpf(1.0f + __builtin_amdgcn_exp2f(2.88539008f * cs)), 1.0f);
            hh[r] = ov * ct;
        }

        unsigned pk01, pk23;
        asm("v_cvt_pk_bf16_f32 %0, %1, %2" : "=v"(pk01) : "v"(hh[0]), "v"(hh[1]));
        asm("v_cvt_pk_bf16_f32 %0, %1, %2" : "=v"(pk23) : "v"(hh[2]), "v"(hh[3]));
        hbuf[cid][p ^ 1][wi[0]] = (short)(pk01 & 0xffffu);
        hbuf[cid][p ^ 1][wi[1]] = (short)(pk01 >> 16);
        hbuf[cid][p ^ 1][wi[2]] = (short)(pk23 & 0xffffu);
        hbuf[cid][p ^ 1][wi[3]] = (short)(pk23 >> 16);
        if (do63) {
            h63buf[cid][p ^ 1][4 * kg + 0] = hh[0];
            h63buf[cid][p ^ 1][4 * kg + 1] = hh[1];
            h63buf[cid][p ^ 1][4 * kg + 2] = hh[2];
            h63buf[cid][p ^ 1][4 * kg + 3] = hh[3];
        }
        xc0 = xn0; xc1 = xn1; xc2 = xn2; xc3 = xn3;
        __syncthreads();
    }

    if (dop) {
        pacc = fmaf(h63buf[cid][0][pb], wl_lds[NT - 1][pa], pacc);
        ws[((size_t)li * NB + bg * 16 + pb) * LENA + pa] = pacc;
    }
}

__global__ __launch_bounds__(256) void reduce_kernel(
    const float* __restrict__ ws, const float* __restrict__ bl, float* __restrict__ out)
{
    int tid = blockIdx.x * 256 + threadIdx.x;    // 0..1023
    if (tid >= NB * LENA) return;
    int b = tid >> 3, a = tid & 7;
    float s = bl[a];
    #pragma unroll
    for (int l2 = 0; l2 < LENA; ++l2) s += ws[((size_t)l2 * NB + b) * LENA + a];
    out[tid] = s;
}

extern "C" void kernel_launch(void* const* d_in, const int* in_sizes, int n_in,
                              void* d_out, int out_size, void* d_ws, size_t ws_size,
                              hipStream_t stream) {
    const float* x   = (const float*)d_in[0];
    const float* hn  = (const float*)d_in[1];
    const float* Wih = (const float*)d_in[2];
    const float* Whh = (const float*)d_in[3];
    const float* bih = (const float*)d_in[4];
    const float* bhh = (const float*)d_in[5];
    const float* Wl  = (const float*)d_in[6];
    const float* bl  = (const float*)d_in[7];
    float* out = (float*)d_out;
    float* ws  = (float*)d_ws;   // 8*128*8*4 = 32 KB

    lstm_mfma2_kernel<<<dim3(32), dim3(512), 0, stream>>>(x, hn, Wih, Whh, bih, bhh, Wl, ws);
    reduce_kernel<<<dim3(4), dim3(256), 0, stream>>>(ws, bl, out);
}

// Round 4
// 596.719 us; speedup vs baseline: 1.4615x; 1.4615x over previous
//
#include <hip/hip_runtime.h>

// Ensemble of 8 LSTMs (H=64, input dim 1) over T=1024, B=128, then (B,T)@Wl^T+bl.
//
// v4: latency hiding via INDEPENDENT co-resident blocks.
//  - 512 blocks x 256 threads; each block = one chain (l, 2 batches), 4 waves.
//    512 blocks / 256 CUs -> 2 independent blocks per CU -> 2 waves/SIMD whose
//    stalls (barrier, LDS latency, MFMA deps) mutually overlap. R3 failed because
//    two chains in ONE block share the block-wide barrier (lockstep).
//  - gates(2x256) = h(2x64) @ Whh^T via mfma_f32_16x16x32_bf16; wave w owns units
//    16w..16w+15 for all 4 gate groups. D rows 2..15 unused (A rows zeroed).
//  - Precision: Whh exact as bf16 hi+lo pair; h rounded to one bf16/step.
//    Logistic constants folded into weights (sigmoid 1/ln2, tanh 2/ln2).
//  - h63 written to an LDS ring each step; projection done once after the loop
//    (no per-step Wl work, no 32KB Wl staging).

#define LENA 8
#define NB 128
#define NT 1024
#define NH 64

typedef __attribute__((ext_vector_type(4))) float f32x4;
typedef __attribute__((ext_vector_type(8))) short bf16x8;

__device__ __forceinline__ short f2bf(float f) {
    unsigned u = __float_as_uint(f);
    unsigned r = (u + 0x7FFFu + ((u >> 16) & 1u)) >> 16;
    return (short)r;
}
__device__ __forceinline__ float bf2f(short s) {
    return __uint_as_float(((unsigned)(unsigned short)s) << 16);
}

__global__ __launch_bounds__(256, 2) void lstm_v4_kernel(
    const float* __restrict__ x, const float* __restrict__ hn,
    const float* __restrict__ Wih, const float* __restrict__ Whh,
    const float* __restrict__ bih, const float* __restrict__ bhh,
    const float* __restrict__ Wl, float* __restrict__ ws)
{
    __shared__ float x2[NT][2];                    // 8 KB: x transposed pairs
    __shared__ __align__(16) short hbuf[2][16 * NH];  // 4 KB: [parity], rows=batch(16, only 0-1 live), swizzled
    __shared__ float ring[NT][2];                  // 8 KB: h63 history per batch
    __shared__ float pws[4][16];                   // partial projection sums

    const int tid = threadIdx.x;
    const int w   = tid >> 6;        // wave 0..3: owns units 16w..16w+15
    const int l   = tid & 63;        // lane
    const int c   = blockIdx.x;      // chain 0..511
    const int li  = c >> 6;          // LSTM index 0..7
    const int bg  = c & 63;          // batch pair index
    const int b0  = bg * 2;

    // ---- staging: x pairs (coalesced read, transposed write) ----
    for (int i = tid; i < 2 * NT; i += 256) {
        int bb = i >> 10, t = i & (NT - 1);
        x2[t][bb] = x[(size_t)(b0 + bb) * NT + t];
    }
    // ---- hbuf init: rows 0,1 = hn, rows 2..15 = 0, both parities ----
    for (int i = tid; i < 2 * 16 * NH; i += 256) {
        int p = i >> 10, rest = i & 1023;
        int b = rest >> 6, u = rest & 63;
        float v = (b < 2) ? hn[((size_t)li * NB + b0 + b) * NH + u] : 0.0f;
        int idx = b * 64 + ((((u >> 3) ^ (b & 7)) << 3) | (u & 7));
        hbuf[p][idx] = f2bf(v);
    }

    // ---- per-lane persistent B fragments (scaled Whh, exact via bf16 hi+lo) ----
    const int bq = l & 15, kg = l >> 4;
    const float RLN2 = 1.44269504f;
    bf16x8 bhf[4][2], blf[4][2];
    float biasv[4], wihv[4];
    #pragma unroll
    for (int G = 0; G < 4; ++G) {
        const float scale = (G == 2) ? 2.0f * RLN2 : RLN2;
        int row = 64 * G + 16 * w + bq;
        const float* rp = Whh + ((size_t)li * 256 + row) * 64 + kg * 8;
        #pragma unroll
        for (int kt = 0; kt < 2; ++kt) {
            const float* q = rp + kt * 32;
            #pragma unroll
            for (int e = 0; e < 8; ++e) {
                float f = scale * q[e];
                short hi = f2bf(f);
                bhf[G][kt][e] = hi;
                blf[G][kt][e] = f2bf(f - bf2f(hi));
            }
        }
        biasv[G] = scale * (bih[li * 256 + row] + bhh[li * 256 + row]);
        wihv[G]  = scale * Wih[li * 256 + row];
    }

    // A-fragment LDS offsets (swizzled): lane reads row bq, k-blocks kg and 4+kg
    const int ia0 = bq * 64 + (((0 + kg) ^ (bq & 7)) << 3);
    const int ia1 = bq * 64 + (((4 + kg) ^ (bq & 7)) << 3);

    // h write indices (active lanes l<16): unit u = 16w+l, batches 0,1
    const int uu  = 16 * w + (l & 15);
    const int kbw = uu >> 3, ulo = uu & 7;
    const int wi0 = ((kbw ^ 0) << 3) | ulo;            // row 0
    const int wi1 = 64 + (((kbw ^ 1) << 3) | ulo);     // row 1
    const bool docell = (l < 16);
    const bool do63   = (w == 3) && (l == 15);          // unit 63 owner

    float cst0 = 0.0f, cst1 = 0.0f;
    float xc0 = 0.0f, xc1 = 0.0f;

    __syncthreads();
    xc0 = x2[0][0];
    xc1 = x2[0][1];

    #pragma unroll 2
    for (int t = 0; t < NT; ++t) {
        const int p = t & 1;

        bf16x8 ah0 = *(const bf16x8*)&hbuf[p][ia0];
        bf16x8 ah1 = *(const bf16x8*)&hbuf[p][ia1];

        int t1 = (t < NT - 1) ? t + 1 : t;
        float xn0 = x2[t1][0];
        float xn1 = x2[t1][1];

        f32x4 acc[4];
        #pragma unroll
        for (int G = 0; G < 4; ++G) {
            f32x4 a;
            a[0] = fmaf(xc0, wihv[G], biasv[G]);
            a[1] = fmaf(xc1, wihv[G], biasv[G]);
            a[2] = a[0];
            a[3] = a[0];
            a = __builtin_amdgcn_mfma_f32_16x16x32_bf16(ah0, bhf[G][0], a, 0, 0, 0);
            a = __builtin_amdgcn_mfma_f32_16x16x32_bf16(ah1, bhf[G][1], a, 0, 0, 0);
            a = __builtin_amdgcn_mfma_f32_16x16x32_bf16(ah0, blf[G][0], a, 0, 0, 0);
            a = __builtin_amdgcn_mfma_f32_16x16x32_bf16(ah1, blf[G][1], a, 0, 0, 0);
            acc[G] = a;
        }

        if (docell) {
            // batch 0 (reg 0) and batch 1 (reg 1); gates pre-scaled for exp2
            float iv0 = __builtin_amdgcn_rcpf(1.0f + __builtin_amdgcn_exp2f(-acc[0][0]));
            float fv0 = __builtin_amdgcn_rcpf(1.0f + __builtin_amdgcn_exp2f(-acc[1][0]));
            float gt0 = fmaf(-2.0f, __builtin_amdgcn_rcpf(1.0f + __builtin_amdgcn_exp2f(acc[2][0])), 1.0f);
            float ov0 = __builtin_amdgcn_rcpf(1.0f + __builtin_amdgcn_exp2f(-acc[3][0]));
            cst0 = fmaf(fv0, cst0, iv0 * gt0);
            float ct0 = fmaf(-2.0f, __builtin_amdgcn_rcpf(1.0f + __builtin_amdgcn_exp2f(2.88539008f * cst0)), 1.0f);
            float hh0 = ov0 * ct0;

            float iv1 = __builtin_amdgcn_rcpf(1.0f + __builtin_amdgcn_exp2f(-acc[0][1]));
            float fv1 = __builtin_amdgcn_rcpf(1.0f + __builtin_amdgcn_exp2f(-acc[1][1]));
            float gt1 = fmaf(-2.0f, __builtin_amdgcn_rcpf(1.0f + __builtin_amdgcn_exp2f(acc[2][1])), 1.0f);
            float ov1 = __builtin_amdgcn_rcpf(1.0f + __builtin_amdgcn_exp2f(-acc[3][1]));
            cst1 = fmaf(fv1, cst1, iv1 * gt1);
            float ct1 = fmaf(-2.0f, __builtin_amdgcn_rcpf(1.0f + __builtin_amdgcn_exp2f(2.88539008f * cst1)), 1.0f);
            float hh1 = ov1 * ct1;

            unsigned pk;
            asm("v_cvt_pk_bf16_f32 %0, %1, %2" : "=v"(pk) : "v"(hh0), "v"(hh1));
            hbuf[p ^ 1][wi0] = (short)(pk & 0xffffu);
            hbuf[p ^ 1][wi1] = (short)(pk >> 16);
            if (do63) {
                ring[t][0] = hh0;
                ring[t][1] = hh1;
            }
        }
        xc0 = xn0;
        xc1 = xn1;
        __syncthreads();
    }

    // ---- projection: out[b][a] partial = sum_t ring[t][b] * Wl[a][t] ----
    float pacc = 0.0f;
    if (l < 16) {
        const int b = l >> 3, a = l & 7;
        const float* wlp = Wl + (size_t)a * NT + w * 256;
        const int tbase = w * 256;
        #pragma unroll 8
        for (int i = 0; i < 256; ++i)
            pacc = fmaf(ring[tbase + i][b], wlp[i], pacc);
        pws[w][l] = pacc;
    }
    __syncthreads();
    if (w == 0 && l < 16) {
        float s = pws[0][l] + pws[1][l] + pws[2][l] + pws[3][l];
        ws[(size_t)c * 16 + l] = s;
    }
}

__global__ __launch_bounds__(256) void reduce_kernel(
    const float* __restrict__ ws, const float* __restrict__ bl, float* __restrict__ out)
{
    int tid = blockIdx.x * 256 + threadIdx.x;    // 0..1023
    if (tid >= NB * LENA) return;
    int b = tid >> 3, a = tid & 7;
    int bg = b >> 1, b_ = b & 1;
    float s = bl[a];
    #pragma unroll
    for (int li = 0; li < LENA; ++li)
        s += ws[((size_t)li * 64 + bg) * 16 + b_ * 8 + a];
    out[tid] = s;
}

extern "C" void kernel_launch(void* const* d_in, const int* in_sizes, int n_in,
                              void* d_out, int out_size, void* d_ws, size_t ws_size,
                              hipStream_t stream) {
    const float* x   = (const float*)d_in[0];
    const float* hn  = (const float*)d_in[1];
    const float* Wih = (const float*)d_in[2];
    const float* Whh = (const float*)d_in[3];
    const float* bih = (const float*)d_in[4];
    const float* bhh = (const float*)d_in[5];
    const float* Wl  = (const float*)d_in[6];
    const float* bl  = (const float*)d_in[7];
    float* out = (float*)d_out;
    float* ws  = (float*)d_ws;   // 512*16*4 = 32 KB

    lstm_v4_kernel<<<dim3(512), dim3(256), 0, stream>>>(x, hn, Wih, Whh, bih, bhh, Wl, ws);
    reduce_kernel<<<dim3(4), dim3(256), 0, stream>>>(ws, bl, out);
}

// Round 5
// 537.506 us; speedup vs baseline: 1.6225x; 1.1102x over previous
//
#include <hip/hip_runtime.h>

// Ensemble of 8 LSTMs (H=64, input dim 1) over T=1024, B=128, then (B,T)@Wl^T+bl.
//
// v5: 512 blocks x 128 threads; block = one chain (l, 2 batches), 2 waves.
//  - gates(16x256) via mfma_f32_16x16x32_bf16. A rows: {b0_hi, b1_hi, b0_lo, b1_lo}
//    (h split hi/lo bf16 -> h effectively fp24-exact); B = Whh single bf16
//    (pre-scaled by 1/ln2, tanh gate 2/ln2). gate = D[b] + D[2+b].
//  - wave w owns tiles n = 4g + 2w + j' (g=0..3, j'=0,1) -> all 4 gate groups of
//    units 32w..32w+31 live in its own lanes 0-15; in-wave LDS round-trip
//    (no barrier) spreads them to 64 lanes: 1 cell per lane.
//  - one __syncthreads per step (cross-wave h exchange only).
//  - h63 ring in LDS; projection after the loop; reduce kernel sums over L.

#define LENA 8
#define NB 128
#define NT 1024
#define NH 64

typedef __attribute__((ext_vector_type(4))) float f32x4;
typedef __attribute__((ext_vector_type(8))) short bf16x8;

__device__ __forceinline__ short f2bf(float f) {
    unsigned u = __float_as_uint(f);
    unsigned r = (u + 0x7FFFu + ((u >> 16) & 1u)) >> 16;
    return (short)r;
}
__device__ __forceinline__ float bf2f(short s) {
    return __uint_as_float(((unsigned)(unsigned short)s) << 16);
}

__global__ __launch_bounds__(128, 2) void lstm_v5_kernel(
    const float* __restrict__ x, const float* __restrict__ hn,
    const float* __restrict__ Wih, const float* __restrict__ Whh,
    const float* __restrict__ bih, const float* __restrict__ bhh,
    const float* __restrict__ Wl, float* __restrict__ ws)
{
    __shared__ float x2[NT][2];                     // 8 KB
    __shared__ float gbuf[2][64][4];                // 2 KB: [b][u][gate]
    __shared__ __align__(16) short harr[2][4][72];  // [parity][row r][u(+pad)]; r = b0hi,b1hi,b0lo,b1lo
    __shared__ float ring[2][NT];                   // 8 KB: h63 history per batch

    const int tid = threadIdx.x;
    const int w   = tid >> 6;        // wave 0/1
    const int l   = tid & 63;        // lane
    const int c   = blockIdx.x;      // chain 0..511
    const int li  = c >> 6;          // LSTM index
    const int bg  = c & 63;          // batch pair
    const int b0  = bg * 2;

    // ---- staging: x ----
    for (int i = tid; i < 2 * NT; i += 128) {
        int bb = i >> 10, t = i & (NT - 1);
        x2[t][bb] = x[(size_t)(b0 + bb) * NT + t];
    }
    // ---- staging: h0 (hi/lo split) ----
    {
        int b = tid >> 6, u = tid & 63;
        float v = hn[((size_t)li * NB + b0 + b) * NH + u];
        short hi = f2bf(v);
        harr[0][b][u] = hi;
        harr[0][2 + b][u] = f2bf(v - bf2f(hi));
    }

    // ---- per-lane persistent B fragments: wave's 8 tiles n = 4g + 2w + j' ----
    const int col = l & 15, kg = l >> 4;
    const float RLN2 = 1.44269504f;
    bf16x8 wf[8][2];
    #pragma unroll
    for (int np = 0; np < 8; ++np) {
        int g = np >> 1, jp = np & 1;
        int n = 4 * g + 2 * w + jp;
        float scale = (g == 2) ? 2.0f * RLN2 : RLN2;
        const float* rp = Whh + ((size_t)li * 256 + 16 * n + col) * 64 + kg * 8;
        #pragma unroll
        for (int kt = 0; kt < 2; ++kt) {
            const float* q = rp + kt * 32;
            #pragma unroll
            for (int e = 0; e < 8; ++e) wf[np][kt][e] = f2bf(scale * q[e]);
        }
    }

    // ---- per-lane cell constants: cell (b_c, u_c) ----
    const int b_c = l >> 5;
    const int jp_c = (l >> 4) & 1;
    const int u_c = (2 * w + jp_c) * 16 + (l & 15);
    float wih4[4], bias4[4];
    #pragma unroll
    for (int g = 0; g < 4; ++g) {
        float sc = (g == 2) ? 2.0f * RLN2 : RLN2;
        int rowc = li * 256 + 64 * g + u_c;
        wih4[g]  = sc * Wih[rowc];
        bias4[g] = sc * (bih[rowc] + bhh[rowc]);
    }

    // A-read short-offsets (row clamped; rows 4-15 garbage-safe)
    const int rcl = (col < 3) ? col : 3;
    const int offA = rcl * 72 + kg * 8;

    const bool gsrc = (l < 16);
    const bool is63 = (u_c == 63);
    float cst = 0.0f;

    __syncthreads();

    #pragma unroll 2
    for (int t = 0; t < NT; ++t) {
        const int p = t & 1;
        const short* hp = &harr[p][0][0];
        bf16x8 a0 = *(const bf16x8*)(hp + offA);
        bf16x8 a1 = *(const bf16x8*)(hp + offA + 32);
        float xb = x2[t][b_c];

        const f32x4 zf = {0.0f, 0.0f, 0.0f, 0.0f};
        f32x4 acc[8];
        #pragma unroll
        for (int np = 0; np < 8; ++np) {
            f32x4 a = __builtin_amdgcn_mfma_f32_16x16x32_bf16(a0, wf[np][0], zf, 0, 0, 0);
            acc[np] = __builtin_amdgcn_mfma_f32_16x16x32_bf16(a1, wf[np][1], a, 0, 0, 0);
        }

        // spread gates: lanes 0-15 hold rows 0-3 (b0hi,b1hi,b0lo,b1lo) per tile
        if (gsrc) {
            #pragma unroll
            for (int b = 0; b < 2; ++b) {
                #pragma unroll
                for (int jp = 0; jp < 2; ++jp) {
                    f32x4 cw;
                    #pragma unroll
                    for (int g = 0; g < 4; ++g) {
                        int np = 2 * g + jp;
                        cw[g] = acc[np][b] + acc[np][2 + b];
                    }
                    *(f32x4*)&gbuf[b][(2 * w + jp) * 16 + l][0] = cw;
                }
            }
        }
        f32x4 gv = *(const f32x4*)&gbuf[b_c][u_c][0];

        float gi = fmaf(xb, wih4[0], gv[0] + bias4[0]);
        float gf = fmaf(xb, wih4[1], gv[1] + bias4[1]);
        float gg = fmaf(xb, wih4[2], gv[2] + bias4[2]);
        float go = fmaf(xb, wih4[3], gv[3] + bias4[3]);

        float iv = __builtin_amdgcn_rcpf(1.0f + __builtin_amdgcn_exp2f(-gi));
        float fv = __builtin_amdgcn_rcpf(1.0f + __builtin_amdgcn_exp2f(-gf));
        float gt = fmaf(-2.0f, __builtin_amdgcn_rcpf(1.0f + __builtin_amdgcn_exp2f(gg)), 1.0f);
        float ov = __builtin_amdgcn_rcpf(1.0f + __builtin_amdgcn_exp2f(-go));
        cst = fmaf(fv, cst, iv * gt);
        float ct = fmaf(-2.0f, __builtin_amdgcn_rcpf(1.0f + __builtin_amdgcn_exp2f(2.88539008f * cst)), 1.0f);
        float hh = ov * ct;

        short hi = f2bf(hh);
        harr[p ^ 1][b_c][u_c] = hi;
        harr[p ^ 1][2 + b_c][u_c] = f2bf(hh - bf2f(hi));
        if (is63) ring[b_c][t] = hh;

        __syncthreads();
    }

    // ---- projection: wave w handles batch w; out[a] = sum_t ring[w][t]*Wl[a][t] ----
    {
        const int a = l & 7, ch = l >> 3;     // 8 outputs x 8 t-chunks of 128
        const float* wlp = Wl + (size_t)a * NT + ch * 128;
        const float* rg  = &ring[w][ch * 128];
        float pacc = 0.0f;
        #pragma unroll 4
        for (int i = 0; i < 32; ++i) {
            float4 rv = *(const float4*)&rg[i * 4];
            float4 wv = *(const float4*)&wlp[i * 4];
            pacc = fmaf(rv.x, wv.x, pacc);
            pacc = fmaf(rv.y, wv.y, pacc);
            pacc = fmaf(rv.z, wv.z, pacc);
            pacc = fmaf(rv.w, wv.w, pacc);
        }
        pacc += __shfl_xor(pacc, 8);
        pacc += __shfl_xor(pacc, 16);
        pacc += __shfl_xor(pacc, 32);
        if (l < 8) ws[(size_t)c * 16 + w * 8 + l] = pacc;
    }
}

__global__ __launch_bounds__(256) void reduce_kernel(
    const float* __restrict__ ws, const float* __restrict__ bl, float* __restrict__ out)
{
    int tid = blockIdx.x * 256 + threadIdx.x;    // 0..1023
    if (tid >= NB * LENA) return;
    int b = tid >> 3, a = tid & 7;
    int bg = b >> 1, b_ = b & 1;
    float s = bl[a];
    #pragma unroll
    for (int li = 0; li < LENA; ++li)
        s += ws[((size_t)li * 64 + bg) * 16 + b_ * 8 + a];
    out[tid] = s;
}

extern "C" void kernel_launch(void* const* d_in, const int* in_sizes, int n_in,
                              void* d_out, int out_size, void* d_ws, size_t ws_size,
                              hipStream_t stream) {
    const float* x   = (const float*)d_in[0];
    const float* hn  = (const float*)d_in[1];
    const float* Wih = (const float*)d_in[2];
    const float* Whh = (const float*)d_in[3];
    const float* bih = (const float*)d_in[4];
    const float* bhh = (const float*)d_in[5];
    const float* Wl  = (const float*)d_in[6];
    const float* bl  = (const float*)d_in[7];
    float* out = (float*)d_out;
    float* ws  = (float*)d_ws;   // 512*16*4 = 32 KB

    lstm_v5_kernel<<<dim3(512), dim3(128), 0, stream>>>(x, hn, Wih, Whh, bih, bhh, Wl, ws);
    reduce_kernel<<<dim3(4), dim3(256), 0, stream>>>(ws, bl, out);
}

// Round 6
// 448.092 us; speedup vs baseline: 1.9463x; 1.1995x over previous
//
#include <hip/hip_runtime.h>

// Ensemble of 8 LSTMs (H=64, input dim 1) over T=1024, B=128, then (B,T)@Wl^T+bl.
//
// v6: one (l,b) chain per SINGLE WAVE; 1024 blocks x 64 threads; no barriers in
// the time loop, no cross-wave traffic.
//  - A-operand = h broadcast to ALL 16 rows (every lane reads the same k-slice
//    of h from LDS -> broadcast, conflict-free). Then every D row is identical,
//    so lane L holds the gates of unit 16*(L>>4) + (L&15) = L itself for each
//    of the 16 (gate x unit-tile) MFMAs -> select its tile via 2 cndmasks.
//    No gate-spread LDS round trip, no masking: 1 cell/lane, full-rate trans.
//  - Whh (scaled by 1/ln2, tanh gate 2/ln2) lives in VGPRs as bf16 B-frags
//    (32 frags = 128 VGPR). h stored as single bf16 (absmax precedent 7.8e-3).
//  - per step: 2 ds_read_b128 (h) + 32 MFMA + 8 cndmask + 10 trans + ds_write_b16.
//  - h63 ring in LDS; projection after the loop; reduce kernel sums over L.

#define LENA 8
#define NB 128
#define NT 1024
#define NH 64

typedef __attribute__((ext_vector_type(4))) float f32x4;
typedef __attribute__((ext_vector_type(8))) short bf16x8;

__device__ __forceinline__ short f2bf(float f) {
    unsigned u = __float_as_uint(f);
    unsigned r = (u + 0x7FFFu + ((u >> 16) & 1u)) >> 16;
    return (short)r;
}

__global__ __launch_bounds__(64, 1) void lstm_v6_kernel(
    const float* __restrict__ x, const float* __restrict__ hn,
    const float* __restrict__ Wih, const float* __restrict__ Whh,
    const float* __restrict__ bih, const float* __restrict__ bhh,
    const float* __restrict__ Wl, float* __restrict__ ws)
{
    __shared__ float x_lds[NT];                  // 4 KB
    __shared__ float ring[NT];                   // 4 KB: h63 history
    __shared__ __align__(16) short hbuf[2][NH];  // 256 B, ping-pong bf16 h

    const int l   = threadIdx.x;      // lane 0..63; owns cell/unit l
    const int li  = blockIdx.x >> 7;  // LSTM index 0..7
    const int b   = blockIdx.x & 127; // batch 0..127
    const int col = l & 15, kg = l >> 4;

    // ---- stage x (coalesced float4) ----
    const float4* xb4 = (const float4*)(x + (size_t)b * NT);
    #pragma unroll
    for (int i = 0; i < 4; ++i) {
        float4 v = xb4[l + 64 * i];
        *(float4*)&x_lds[(l + 64 * i) * 4] = v;
    }
    // ---- stage h0 (bf16) ----
    hbuf[0][l] = f2bf(hn[((size_t)li * NB + b) * NH + l]);

    const float RLN2 = 1.44269504f;
    // ---- persistent B-frags: wf[gate][unit-tile][k-half], bf16, pre-scaled ----
    bf16x8 wf[4][4][2];
    #pragma unroll
    for (int g = 0; g < 4; ++g) {
        const float sc = (g == 2) ? 2.0f * RLN2 : RLN2;
        #pragma unroll
        for (int tt = 0; tt < 4; ++tt) {
            const float* rp = Whh + ((size_t)li * 256 + 64 * g + 16 * tt + col) * 64 + kg * 8;
            #pragma unroll
            for (int kh = 0; kh < 2; ++kh) {
                const float* q = rp + kh * 32;
                bf16x8 f;
                #pragma unroll
                for (int e = 0; e < 8; ++e) f[e] = f2bf(sc * q[e]);
                wf[g][tt][kh] = f;
            }
        }
    }
    // ---- per-cell constants (cell = unit l) ----
    float wih4[4], bias4[4];
    #pragma unroll
    for (int g = 0; g < 4; ++g) {
        const float sc = (g == 2) ? 2.0f * RLN2 : RLN2;
        int rowc = li * 256 + 64 * g + l;
        wih4[g]  = sc * Wih[rowc];
        bias4[g] = sc * (bih[rowc] + bhh[rowc]);
    }

    float cst = 0.0f;
    const bool is63 = (l == 63);
    const bool selb0 = (kg & 1) != 0;
    const bool selb1 = (kg & 2) != 0;
    __syncthreads();   // single wave; trivial

    for (int t = 0; t < NT; ++t) {
        const int p = t & 1;
        const float xv = x_lds[t];
        bf16x8 a0 = *(const bf16x8*)&hbuf[p][kg * 8];        // h[k 0:32) slice
        bf16x8 a1 = *(const bf16x8*)&hbuf[p][32 + kg * 8];   // h[k 32:64) slice

        float gs[4];
        #pragma unroll
        for (int g = 0; g < 4; ++g) {
            const f32x4 z = {0.0f, 0.0f, 0.0f, 0.0f};
            f32x4 c0 = __builtin_amdgcn_mfma_f32_16x16x32_bf16(a0, wf[g][0][0], z, 0, 0, 0);
            c0 = __builtin_amdgcn_mfma_f32_16x16x32_bf16(a1, wf[g][0][1], c0, 0, 0, 0);
            f32x4 c1 = __builtin_amdgcn_mfma_f32_16x16x32_bf16(a0, wf[g][1][0], z, 0, 0, 0);
            c1 = __builtin_amdgcn_mfma_f32_16x16x32_bf16(a1, wf[g][1][1], c1, 0, 0, 0);
            f32x4 c2 = __builtin_amdgcn_mfma_f32_16x16x32_bf16(a0, wf[g][2][0], z, 0, 0, 0);
            c2 = __builtin_amdgcn_mfma_f32_16x16x32_bf16(a1, wf[g][2][1], c2, 0, 0, 0);
            f32x4 c3 = __builtin_amdgcn_mfma_f32_16x16x32_bf16(a0, wf[g][3][0], z, 0, 0, 0);
            c3 = __builtin_amdgcn_mfma_f32_16x16x32_bf16(a1, wf[g][3][1], c3, 0, 0, 0);
            float va = selb0 ? c1[0] : c0[0];
            float vb = selb0 ? c3[0] : c2[0];
            gs[g] = selb1 ? vb : va;
        }

        float gi = fmaf(xv, wih4[0], gs[0] + bias4[0]);
        float gf = fmaf(xv, wih4[1], gs[1] + bias4[1]);
        float gg = fmaf(xv, wih4[2], gs[2] + bias4[2]);
        float go = fmaf(xv, wih4[3], gs[3] + bias4[3]);

        float iv = __builtin_amdgcn_rcpf(1.0f + __builtin_amdgcn_exp2f(-gi));
        float fv = __builtin_amdgcn_rcpf(1.0f + __builtin_amdgcn_exp2f(-gf));
        float gt = fmaf(-2.0f, __builtin_amdgcn_rcpf(1.0f + __builtin_amdgcn_exp2f(gg)), 1.0f);
        float ov = __builtin_amdgcn_rcpf(1.0f + __builtin_amdgcn_exp2f(-go));
        cst = fmaf(fv, cst, iv * gt);
        float ct = fmaf(-2.0f, __builtin_amdgcn_rcpf(1.0f + __builtin_amdgcn_exp2f(2.88539008f * cst)), 1.0f);
        float hh = ov * ct;

        hbuf[p ^ 1][l] = f2bf(hh);
        if (is63) ring[t] = hh;
    }

    __syncthreads();   // single wave; trivial

    // ---- projection: out[a] = sum_t ring[t] * Wl[a][t] ----
    {
        const int a = l & 7, ch = l >> 3;     // 8 outputs x 8 t-chunks of 128
        const float* wlp = Wl + (size_t)a * NT + ch * 128;
        const float* rg  = &ring[ch * 128];
        float pacc = 0.0f;
        #pragma unroll 4
        for (int i = 0; i < 32; ++i) {
            float4 rv = *(const float4*)&rg[i * 4];
            float4 wv = *(const float4*)&wlp[i * 4];
            pacc = fmaf(rv.x, wv.x, pacc);
            pacc = fmaf(rv.y, wv.y, pacc);
            pacc = fmaf(rv.z, wv.z, pacc);
            pacc = fmaf(rv.w, wv.w, pacc);
        }
        pacc += __shfl_xor(pacc, 8);
        pacc += __shfl_xor(pacc, 16);
        pacc += __shfl_xor(pacc, 32);
        if (l < 8) ws[(size_t)blockIdx.x * 8 + l] = pacc;
    }
}

__global__ __launch_bounds__(256) void reduce_kernel(
    const float* __restrict__ ws, const float* __restrict__ bl, float* __restrict__ out)
{
    int tid = blockIdx.x * 256 + threadIdx.x;    // 0..1023
    if (tid >= NB * LENA) return;
    int b = tid >> 3, a = tid & 7;
    float s = bl[a];
    #pragma unroll
    for (int li = 0; li < LENA; ++li)
        s += ws[((size_t)li * NB + b) * 8 + a];
    out[tid] = s;
}

extern "C" void kernel_launch(void* const* d_in, const int* in_sizes, int n_in,
                              void* d_out, int out_size, void* d_ws, size_t ws_size,
                              hipStream_t stream) {
    const float* x   = (const float*)d_in[0];
    const float* hn  = (const float*)d_in[1];
    const float* Wih = (const float*)d_in[2];
    const float* Whh = (const float*)d_in[3];
    const float* bih = (const float*)d_in[4];
    const float* bhh = (const float*)d_in[5];
    const float* Wl  = (const float*)d_in[6];
    const float* bl  = (const float*)d_in[7];
    float* out = (float*)d_out;
    float* ws  = (float*)d_ws;   // 1024*8*4 = 32 KB

    lstm_v6_kernel<<<dim3(1024), dim3(64), 0, stream>>>(x, hn, Wih, Whh, bih, bhh, Wl, ws);
    reduce_kernel<<<dim3(4), dim3(256), 0, stream>>>(ws, bl, out);
}